// Round 3
// baseline (221.219 us; speedup 1.0000x reference)
//
#include <hip/hip_runtime.h>
#include <hip/hip_cooperative_groups.h>
#include <math.h>

namespace cg = cooperative_groups;

#define DIM 1024
#define NB  256
#define NF  64

// ws layout (all fully overwritten every call, no init needed):
// thres : [0     , 4 KB)
// diag  : [4 KB  , 8 KB)
// dpart : [8 KB  , 8 KB + 1 MB)    256 x 1024 f32 per-block partial col sums
// vmean : [8KB+1MB, 8KB+2MB)       256 x 1024 f32

__global__ __launch_bounds__(1024, 4)
void kfused(const float* __restrict__ txt, const float* __restrict__ vid,
            const float* __restrict__ emb, const float* __restrict__ simw,
            const float* __restrict__ tempw,
            float* __restrict__ thres, float* __restrict__ diag,
            float* __restrict__ dpart, float* __restrict__ vmean,
            float* __restrict__ out) {
    cg::grid_group grid = cg::this_grid();
    const int b    = blockIdx.x;   // 0..255
    const int t    = threadIdx.x;  // 0..1023
    const int lane = t & 63;
    const int wav  = t >> 6;       // 0..15

    __shared__ float4 s_acc[768];            // P1 cross-wave combine (12 KB)
    __shared__ double s_ls[16], s_lq[16];    // P2 reduction slots
    __shared__ float  s_a[4][DIM];           // P3 per-row dlw values (16 KB)
    __shared__ float  s_red[16];             // generic per-wave reduction slots
    __shared__ float  s_td[DIM];             // P4 txt[i,:]*diag
    __shared__ float  s_row[NB];             // P4 sim row

    // ================= P1: vmean[b][d] = mean_f vid[b][f][d]  (64 MB HBM) ==========
    {
        int tt = t & 255, fh = t >> 8;                 // tt owns d=4tt..4tt+3
        const float* base = vid + (size_t)b * NF * DIM + (size_t)fh * 16 * DIM + tt * 4;
        float4 a = {0.f, 0.f, 0.f, 0.f};
        #pragma unroll
        for (int f = 0; f < 16; ++f) {
            float4 v = *(const float4*)(base + (size_t)f * DIM);
            a.x += v.x; a.y += v.y; a.z += v.z; a.w += v.w;
        }
        if (fh > 0) s_acc[(fh - 1) * 256 + tt] = a;
        __syncthreads();
        if (fh == 0) {
            float4 b1 = s_acc[tt], b2 = s_acc[256 + tt], b3 = s_acc[512 + tt];
            a.x = (a.x + b1.x + b2.x + b3.x) * (1.0f / 64.0f);
            a.y = (a.y + b1.y + b2.y + b3.y) * (1.0f / 64.0f);
            a.z = (a.z + b1.z + b2.z + b3.z) * (1.0f / 64.0f);
            a.w = (a.w + b1.w + b2.w + b3.w) * (1.0f / 64.0f);
            *(float4*)(vmean + (size_t)b * DIM + tt * 4) = a;
        }
    }
    __syncthreads();

    // ================= P2: thres[r], rows r = 4b..4b+3 (quarter-block per row) ======
    {
        int sub = t >> 8, tt = t & 255;
        int r = 4 * b + sub;
        float4 e = *(const float4*)(emb + (size_t)r * DIM + tt * 4);
        float w0 = 1.0f / (1.0f + expf(-e.x));
        float w1 = 1.0f / (1.0f + expf(-e.y));
        float w2 = 1.0f / (1.0f + expf(-e.z));
        float w3 = 1.0f / (1.0f + expf(-e.w));
        double s  = (double)w0 + w1 + w2 + w3;
        double sq = (double)w0*w0 + (double)w1*w1 + (double)w2*w2 + (double)w3*w3;
        #pragma unroll
        for (int off = 32; off > 0; off >>= 1) {
            s  += __shfl_down(s, off);
            sq += __shfl_down(sq, off);
        }
        if (lane == 0) { s_ls[wav] = s; s_lq[wav] = sq; }
        __syncthreads();
        if (tt == 0) {   // one thread per quarter (wav = 4*sub, lane 0)
            double S = s_ls[4*sub] + s_ls[4*sub+1] + s_ls[4*sub+2] + s_ls[4*sub+3];
            double Q = s_lq[4*sub] + s_lq[4*sub+1] + s_lq[4*sub+2] + s_lq[4*sub+3];
            double mean = S / DIM;
            double var  = (Q - S * S / DIM) / (DIM - 1);
            if (var < 0.0) var = 0.0;
            thres[r] = (float)(mean + (double)simw[r] * sqrt(var));
        }
    }
    grid.sync();   // all thres visible

    // ================= P3: block-partial column sums of dlw =========================
    {
        int sub = t >> 8, tt = t & 255;
        int r = 4 * b + sub;
        float et = expf(tempw[0]);
        float4 th = *(const float4*)(thres + tt * 4);
        float4 e  = *(const float4*)(emb + (size_t)r * DIM + tt * 4);
        float w0 = 1.0f / (1.0f + expf(-e.x));
        float w1 = 1.0f / (1.0f + expf(-e.y));
        float w2 = 1.0f / (1.0f + expf(-e.z));
        float w3 = 1.0f / (1.0f + expf(-e.w));
        float m0 = tanhf(expf(et * (w0 - th.x))) * w0;
        float m1 = tanhf(expf(et * (w1 - th.y))) * w1;
        float m2 = tanhf(expf(et * (w2 - th.z))) * w2;
        float m3 = tanhf(expf(et * (w3 - th.w))) * w3;
        float ss = m0*m0 + m1*m1 + m2*m2 + m3*m3;
        #pragma unroll
        for (int off = 32; off > 0; off >>= 1) ss += __shfl_down(ss, off);
        if (lane == 0) s_red[wav] = ss;
        __syncthreads();
        float rn = 1.0f / (sqrtf(s_red[4*sub] + s_red[4*sub+1] +
                                 s_red[4*sub+2] + s_red[4*sub+3]) + 1e-8f);
        float4 dl = { m0 * rn, m1 * rn, m2 * rn, m3 * rn };
        *(float4*)&s_a[sub][tt * 4] = dl;
        __syncthreads();
        dpart[(size_t)b * DIM + t] = s_a[0][t] + s_a[1][t] + s_a[2][t] + s_a[3][t];
    }
    grid.sync();   // all dpart visible

    // ================= P3b: diag[c] = sum_b dpart[b][c], cols 4b..4b+3 ==============
    {
        int sub = t >> 8, s = t & 255;
        int col = 4 * b + sub;
        float v = dpart[(size_t)s * DIM + col];
        #pragma unroll
        for (int off = 32; off > 0; off >>= 1) v += __shfl_down(v, off);
        if (lane == 0) s_red[wav] = v;
        __syncthreads();
        if ((t & 255) == 0)
            diag[col] = s_red[4*sub] + s_red[4*sub+1] + s_red[4*sub+2] + s_red[4*sub+3];
    }
    grid.sync();   // diag visible

    // ================= P4: sim[b][:] = <txt[b]*diag, vmean[j]>, fused L2-norm =======
    {
        s_td[t] = txt[(size_t)b * DIM + t] * diag[t];
        __syncthreads();
        const float4* tdv = (const float4*)s_td;
        // wave w computes j = 16w .. 16w+15; lanes cover K coalesced (1 KB/instr)
        #pragma unroll 4
        for (int jj = 0; jj < 16; ++jj) {
            int j = wav * 16 + jj;
            const float4* vp = (const float4*)(vmean + (size_t)j * DIM);
            float p = 0.f;
            #pragma unroll
            for (int c = 0; c < 4; ++c) {
                float4 v = vp[c * 64 + lane];
                float4 a = tdv[c * 64 + lane];
                p = fmaf(v.x, a.x, p); p = fmaf(v.y, a.y, p);
                p = fmaf(v.z, a.z, p); p = fmaf(v.w, a.w, p);
            }
            #pragma unroll
            for (int off = 32; off > 0; off >>= 1) p += __shfl_down(p, off);
            if (lane == 0) s_row[j] = p;
        }
        __syncthreads();
        float sv = (t < NB) ? s_row[t] : 0.f;
        float ss = sv * sv;
        #pragma unroll
        for (int off = 32; off > 0; off >>= 1) ss += __shfl_down(ss, off);
        if (lane == 0) s_red[wav] = ss;
        __syncthreads();
        float tot = 0.f;
        #pragma unroll
        for (int w = 0; w < 16; ++w) tot += s_red[w];
        if (t < NB)
            out[(size_t)b * NB + t] = sv / (sqrtf(tot) + 1e-8f);
    }
}

extern "C" void kernel_launch(void* const* d_in, const int* in_sizes, int n_in,
                              void* d_out, int out_size, void* d_ws, size_t ws_size,
                              hipStream_t stream) {
    const float* txt   = (const float*)d_in[0];   // [256,1024]
    const float* vid   = (const float*)d_in[1];   // [256,64,1024]
    const float* emb   = (const float*)d_in[2];   // [1024,1024]
    const float* simw  = (const float*)d_in[3];   // [1,1024]
    const float* tempw = (const float*)d_in[4];   // [1,1]
    float* out = (float*)d_out;                   // [256,256]

    char* ws = (char*)d_ws;
    float* thres = (float*)(ws);                          // 4 KB
    float* diag  = (float*)(ws + 4096);                   // 4 KB
    float* dpart = (float*)(ws + 8192);                   // 1 MB
    float* vmean = (float*)(ws + 8192 + (1 << 20));       // 1 MB

    void* args[] = { (void*)&txt, (void*)&vid, (void*)&emb, (void*)&simw,
                     (void*)&tempw, (void*)&thres, (void*)&diag, (void*)&dpart,
                     (void*)&vmean, (void*)&out };
    hipLaunchCooperativeKernel((const void*)kfused, dim3(NB), dim3(1024),
                               args, 0, stream);
}

// Round 4
// 123.657 us; speedup vs baseline: 1.7890x; 1.7890x over previous
//
#include <hip/hip_runtime.h>
#include <math.h>

#define DIM 1024
#define NB  256
#define NF  64
#define KS  8          // split-K slices
#define TK  (DIM/KS)   // 128 k per GEMM block
#define PADK 132       // LDS leading dim (multiple of 4 for float4 alignment)

// ws layout (total ~7.01 MB, every byte written before read each call):
// thres : [0, 4 KB)
// diag  : [4 KB, 8 KB)
// dlw   : [8 KB, 8 KB + 4 MB)          1024 x 1024 row-normalized mask*w
// vmean : [+4 MB, +5 MB)               256 x 1024
// part  : [+5 MB, +7 MB)               8 x 256 x 256 split-K partials

// ---- K1: blocks 0..255 also compute vmean[j]; ALL blocks compute thres[row b] ----
__global__ __launch_bounds__(256)
void k1(const float* __restrict__ vid, const float* __restrict__ emb,
        const float* __restrict__ simw, float* __restrict__ vmean,
        float* __restrict__ thres) {
    int b = blockIdx.x, t = threadIdx.x;

    if (b < NB) {   // vmean[b][d] = mean_f vid[b][f][d]   (the 64 MB HBM read)
        const float* base = vid + (size_t)b * NF * DIM + t * 4;
        float4 a0 = {0.f,0.f,0.f,0.f}, a1 = {0.f,0.f,0.f,0.f};
        #pragma unroll 8
        for (int f = 0; f < NF; f += 2) {
            float4 v0 = *(const float4*)(base + (size_t)f * DIM);
            float4 v1 = *(const float4*)(base + (size_t)(f + 1) * DIM);
            a0.x += v0.x; a0.y += v0.y; a0.z += v0.z; a0.w += v0.w;
            a1.x += v1.x; a1.y += v1.y; a1.z += v1.z; a1.w += v1.w;
        }
        float4 a = { (a0.x + a1.x) * (1.0f/64.0f), (a0.y + a1.y) * (1.0f/64.0f),
                     (a0.z + a1.z) * (1.0f/64.0f), (a0.w + a1.w) * (1.0f/64.0f) };
        *(float4*)(vmean + (size_t)b * DIM + t * 4) = a;
    }

    // thres[b] = mean + simw[b]*std(ddof=1) of sigmoid(emb[b,:])
    float4 e = *(const float4*)(emb + (size_t)b * DIM + t * 4);
    float w0 = 1.0f / (1.0f + expf(-e.x));
    float w1 = 1.0f / (1.0f + expf(-e.y));
    float w2 = 1.0f / (1.0f + expf(-e.z));
    float w3 = 1.0f / (1.0f + expf(-e.w));
    double s  = (double)w0 + w1 + w2 + w3;
    double sq = (double)w0*w0 + (double)w1*w1 + (double)w2*w2 + (double)w3*w3;
    #pragma unroll
    for (int off = 32; off > 0; off >>= 1) {
        s  += __shfl_down(s, off);
        sq += __shfl_down(sq, off);
    }
    __shared__ double ls[4], lq[4];
    int wid = t >> 6, lane = t & 63;
    if (lane == 0) { ls[wid] = s; lq[wid] = sq; }
    __syncthreads();
    if (t == 0) {
        double S = ls[0] + ls[1] + ls[2] + ls[3];
        double Q = lq[0] + lq[1] + lq[2] + lq[3];
        double mean = S / DIM;
        double var  = (Q - S * S / DIM) / (DIM - 1);
        if (var < 0.0) var = 0.0;
        thres[b] = (float)(mean + (double)simw[b] * sqrt(var));
    }
}

// ---- K2: dlw[r][:] = l2norm_row( mask(r,:) * w(r,:) ), one block per row ---------
__global__ __launch_bounds__(256)
void k2(const float* __restrict__ emb, const float* __restrict__ thres,
        const float* __restrict__ tempw, float* __restrict__ dlw) {
    int r = blockIdx.x, t = threadIdx.x;
    float et = expf(tempw[0]);
    float4 th = *(const float4*)(thres + t * 4);      // thres indexed by COLUMN
    float4 e  = *(const float4*)(emb + (size_t)r * DIM + t * 4);
    float w0 = 1.0f / (1.0f + expf(-e.x));
    float w1 = 1.0f / (1.0f + expf(-e.y));
    float w2 = 1.0f / (1.0f + expf(-e.z));
    float w3 = 1.0f / (1.0f + expf(-e.w));
    float m0 = tanhf(expf(et * (w0 - th.x))) * w0;
    float m1 = tanhf(expf(et * (w1 - th.y))) * w1;
    float m2 = tanhf(expf(et * (w2 - th.z))) * w2;
    float m3 = tanhf(expf(et * (w3 - th.w))) * w3;
    float ss = m0*m0 + m1*m1 + m2*m2 + m3*m3;
    #pragma unroll
    for (int off = 32; off > 0; off >>= 1) ss += __shfl_down(ss, off);
    __shared__ float red[4];
    int wid = t >> 6, lane = t & 63;
    if (lane == 0) red[wid] = ss;
    __syncthreads();
    float rn = 1.0f / (sqrtf(red[0] + red[1] + red[2] + red[3]) + 1e-8f);
    float4 dl = { m0 * rn, m1 * rn, m2 * rn, m3 * rn };
    *(float4*)(dlw + (size_t)r * DIM + t * 4) = dl;
}

// ---- K3: diag[c] = sum_r dlw[r][c]; 64 blocks x 16 cols ---------------------------
__global__ __launch_bounds__(256)
void k3(const float* __restrict__ dlw, float* __restrict__ diag) {
    int b = blockIdx.x;          // cols 16b .. 16b+15
    int t = threadIdx.x;
    int c16 = t & 15, rg = t >> 4;   // 16 row-groups x 64 rows
    int col = b * 16 + c16;
    float s = 0.f;
    #pragma unroll 8
    for (int i = 0; i < 64; ++i)
        s += dlw[(size_t)(rg * 64 + i) * DIM + col];
    __shared__ float red[16][16];
    red[rg][c16] = s;
    __syncthreads();
    if (rg == 0) {
        float tot = 0.f;
        #pragma unroll
        for (int g = 0; g < 16; ++g) tot += red[g][c16];
        diag[col] = tot;
    }
}

// ---- K4: split-K GEMM, 512 blocks: 64 tiles (8x8 of 32x32) x 8 k-slices ----------
__global__ __launch_bounds__(256)
void k4(const float* __restrict__ txt, const float* __restrict__ diag,
        const float* __restrict__ vmean, float* __restrict__ part) {
    __shared__ float Tt[32][PADK];
    __shared__ float Vt[32][PADK];
    int bx   = blockIdx.x;
    int tile = bx & 63;
    int ks   = bx >> 6;
    int i0 = (tile & 7) * 32, j0 = (tile >> 3) * 32;
    int kb = ks * TK;
    int t  = threadIdx.x;
    int tx = t & 15, ty = t >> 4;
    #pragma unroll
    for (int p = 0; p < 4; ++p) {
        int fid = p * 256 + t;       // 0..1023 float4 slots
        int row = fid >> 5;          // 0..31
        int kq  = fid & 31;          // float4 index within 128-k slice
        float4 a  = *(const float4*)(txt + (size_t)(i0 + row) * DIM + kb + kq * 4);
        float4 dg = *(const float4*)(diag + kb + kq * 4);
        a.x *= dg.x; a.y *= dg.y; a.z *= dg.z; a.w *= dg.w;
        *(float4*)&Tt[row][kq * 4] = a;
        float4 bb = *(const float4*)(vmean + (size_t)(j0 + row) * DIM + kb + kq * 4);
        *(float4*)&Vt[row][kq * 4] = bb;
    }
    __syncthreads();
    float acc00 = 0.f, acc01 = 0.f, acc10 = 0.f, acc11 = 0.f;
    #pragma unroll
    for (int k4i = 0; k4i < TK / 4; ++k4i) {
        float4 a0 = *(float4*)&Tt[ty * 2 + 0][k4i * 4];
        float4 a1 = *(float4*)&Tt[ty * 2 + 1][k4i * 4];
        float4 b0 = *(float4*)&Vt[tx * 2 + 0][k4i * 4];
        float4 b1 = *(float4*)&Vt[tx * 2 + 1][k4i * 4];
        acc00 = fmaf(a0.x, b0.x, acc00); acc00 = fmaf(a0.y, b0.y, acc00);
        acc00 = fmaf(a0.z, b0.z, acc00); acc00 = fmaf(a0.w, b0.w, acc00);
        acc01 = fmaf(a0.x, b1.x, acc01); acc01 = fmaf(a0.y, b1.y, acc01);
        acc01 = fmaf(a0.z, b1.z, acc01); acc01 = fmaf(a0.w, b1.w, acc01);
        acc10 = fmaf(a1.x, b0.x, acc10); acc10 = fmaf(a1.y, b0.y, acc10);
        acc10 = fmaf(a1.z, b0.z, acc10); acc10 = fmaf(a1.w, b0.w, acc10);
        acc11 = fmaf(a1.x, b1.x, acc11); acc11 = fmaf(a1.y, b1.y, acc11);
        acc11 = fmaf(a1.z, b1.z, acc11); acc11 = fmaf(a1.w, b1.w, acc11);
    }
    size_t base = (size_t)ks * (NB * NB);
    part[base + (size_t)(i0 + ty*2 + 0) * NB + j0 + tx*2 + 0] = acc00;
    part[base + (size_t)(i0 + ty*2 + 0) * NB + j0 + tx*2 + 1] = acc01;
    part[base + (size_t)(i0 + ty*2 + 1) * NB + j0 + tx*2 + 0] = acc10;
    part[base + (size_t)(i0 + ty*2 + 1) * NB + j0 + tx*2 + 1] = acc11;
}

// ---- K5: sum split-K partials + row-wise L2 norm ---------------------------------
__global__ __launch_bounds__(256)
void k5(const float* __restrict__ part, float* __restrict__ out) {
    int i = blockIdx.x, j = threadIdx.x;
    float s = 0.f;
    #pragma unroll
    for (int ks = 0; ks < KS; ++ks)
        s += part[(size_t)ks * (NB * NB) + (size_t)i * NB + j];
    float ss = s * s;
    #pragma unroll
    for (int off = 32; off > 0; off >>= 1) ss += __shfl_down(ss, off);
    __shared__ float red[4];
    int wid = j >> 6, lane = j & 63;
    if (lane == 0) red[wid] = ss;
    __syncthreads();
    float norm = sqrtf(red[0] + red[1] + red[2] + red[3]);
    out[(size_t)i * NB + j] = s / (norm + 1e-8f);
}

extern "C" void kernel_launch(void* const* d_in, const int* in_sizes, int n_in,
                              void* d_out, int out_size, void* d_ws, size_t ws_size,
                              hipStream_t stream) {
    const float* txt   = (const float*)d_in[0];   // [256,1024]
    const float* vid   = (const float*)d_in[1];   // [256,64,1024]
    const float* emb   = (const float*)d_in[2];   // [1024,1024]
    const float* simw  = (const float*)d_in[3];   // [1,1024]
    const float* tempw = (const float*)d_in[4];   // [1,1]
    float* out = (float*)d_out;                   // [256,256]

    char* ws = (char*)d_ws;
    float* thres = (float*)(ws);                                   // 4 KB
    float* diag  = (float*)(ws + 4096);                            // 4 KB
    float* dlw   = (float*)(ws + 8192);                            // 4 MB
    float* vmean = (float*)(ws + 8192 + (4u << 20));               // 1 MB
    float* part  = (float*)(ws + 8192 + (5u << 20));               // 2 MB

    k1<<<1024, 256, 0, stream>>>(vid, emb, simw, vmean, thres);
    k2<<<1024, 256, 0, stream>>>(emb, thres, tempw, dlw);
    k3<<<64,   256, 0, stream>>>(dlw, diag);
    k4<<<512,  256, 0, stream>>>(txt, diag, vmean, part);
    k5<<<256,  256, 0, stream>>>(part, out);
}

// Round 5
// 122.802 us; speedup vs baseline: 1.8014x; 1.0070x over previous
//
#include <hip/hip_runtime.h>
#include <math.h>

#define DIM 1024
#define NB  256
#define NF  64
#define KS  8          // split-K slices
#define TK  (DIM/KS)   // 128 k per GEMM block
#define PADK 132       // LDS leading dim

// ws layout (total ~4.01 MB, every byte written before read each call):
// thres : [0, 4 KB)
// diag  : [4 KB, 8 KB)
// cpart : [8 KB, 8 KB + 1 MB)    256 x 1024 partial col sums of dlw (4 rows/block)
// vmean : [+1 MB, +2 MB)         256 x 1024
// part  : [+2 MB, +4 MB)         8 x 256 x 256 split-K partials

// ---- K1: blocks 0..255 compute vmean[b]; ALL 1024 blocks compute thres[b] --------
__global__ __launch_bounds__(256)
void k1(const float* __restrict__ vid, const float* __restrict__ emb,
        const float* __restrict__ simw, float* __restrict__ vmean,
        float* __restrict__ thres) {
    int b = blockIdx.x, t = threadIdx.x;

    if (b < NB) {   // vmean[b][d] = mean_f vid[b][f][d]   (the 64 MB HBM read)
        const float* base = vid + (size_t)b * NF * DIM + t * 4;
        float4 a0 = {0.f,0.f,0.f,0.f}, a1 = {0.f,0.f,0.f,0.f};
        #pragma unroll 8
        for (int f = 0; f < NF; f += 2) {
            float4 v0 = *(const float4*)(base + (size_t)f * DIM);
            float4 v1 = *(const float4*)(base + (size_t)(f + 1) * DIM);
            a0.x += v0.x; a0.y += v0.y; a0.z += v0.z; a0.w += v0.w;
            a1.x += v1.x; a1.y += v1.y; a1.z += v1.z; a1.w += v1.w;
        }
        float4 a = { (a0.x + a1.x) * (1.0f/64.0f), (a0.y + a1.y) * (1.0f/64.0f),
                     (a0.z + a1.z) * (1.0f/64.0f), (a0.w + a1.w) * (1.0f/64.0f) };
        *(float4*)(vmean + (size_t)b * DIM + t * 4) = a;
    }

    // thres[b] = mean + simw[b]*std(ddof=1) of sigmoid(emb[b,:]) — hidden under vid read
    float4 e = *(const float4*)(emb + (size_t)b * DIM + t * 4);
    float w0 = 1.0f / (1.0f + expf(-e.x));
    float w1 = 1.0f / (1.0f + expf(-e.y));
    float w2 = 1.0f / (1.0f + expf(-e.z));
    float w3 = 1.0f / (1.0f + expf(-e.w));
    double s  = (double)w0 + w1 + w2 + w3;
    double sq = (double)w0*w0 + (double)w1*w1 + (double)w2*w2 + (double)w3*w3;
    #pragma unroll
    for (int off = 32; off > 0; off >>= 1) {
        s  += __shfl_down(s, off);
        sq += __shfl_down(sq, off);
    }
    __shared__ double ls[4], lq[4];
    int wid = t >> 6, lane = t & 63;
    if (lane == 0) { ls[wid] = s; lq[wid] = sq; }
    __syncthreads();
    if (t == 0) {
        double S = ls[0] + ls[1] + ls[2] + ls[3];
        double Q = lq[0] + lq[1] + lq[2] + lq[3];
        double mean = S / DIM;
        double var  = (Q - S * S / DIM) / (DIM - 1);
        if (var < 0.0) var = 0.0;
        thres[b] = (float)(mean + (double)simw[b] * sqrt(var));
    }
}

// ---- K2: 256 blocks x 4 rows: dlw rows + register-accumulated partial col sums ----
// tanh(y) for y>=0 via 1 - 2/(e^{2y}+1); __expf(inf)=inf -> tanh -> 1 correctly.
__global__ __launch_bounds__(256)
void k2(const float* __restrict__ emb, const float* __restrict__ thres,
        const float* __restrict__ tempw, float* __restrict__ cpart) {
    int b = blockIdx.x, t = threadIdx.x;
    float et = expf(tempw[0]);
    float4 th = *(const float4*)(thres + t * 4);      // thres indexed by COLUMN
    float4 acc = {0.f, 0.f, 0.f, 0.f};
    __shared__ float red[4];
    int wid = t >> 6, lane = t & 63;
    #pragma unroll
    for (int rr = 0; rr < 4; ++rr) {
        int r = b * 4 + rr;
        float4 e = *(const float4*)(emb + (size_t)r * DIM + t * 4);
        float w0 = 1.0f / (1.0f + __expf(-e.x));
        float w1 = 1.0f / (1.0f + __expf(-e.y));
        float w2 = 1.0f / (1.0f + __expf(-e.z));
        float w3 = 1.0f / (1.0f + __expf(-e.w));
        float y0 = __expf(et * (w0 - th.x));
        float y1 = __expf(et * (w1 - th.y));
        float y2 = __expf(et * (w2 - th.z));
        float y3 = __expf(et * (w3 - th.w));
        float m0 = (1.0f - 2.0f / (__expf(2.0f * y0) + 1.0f)) * w0;
        float m1 = (1.0f - 2.0f / (__expf(2.0f * y1) + 1.0f)) * w1;
        float m2 = (1.0f - 2.0f / (__expf(2.0f * y2) + 1.0f)) * w2;
        float m3 = (1.0f - 2.0f / (__expf(2.0f * y3) + 1.0f)) * w3;
        float ss = m0*m0 + m1*m1 + m2*m2 + m3*m3;
        #pragma unroll
        for (int off = 32; off > 0; off >>= 1) ss += __shfl_down(ss, off);
        if (lane == 0) red[wid] = ss;
        __syncthreads();
        float rn = 1.0f / (sqrtf(red[0] + red[1] + red[2] + red[3]) + 1e-8f);
        acc.x += m0 * rn; acc.y += m1 * rn; acc.z += m2 * rn; acc.w += m3 * rn;
        __syncthreads();   // guard red[] reuse next row
    }
    *(float4*)(cpart + (size_t)b * DIM + t * 4) = acc;
}

// ---- K3: diag[c] = sum over 256 cpart rows; 64 blocks x 16 cols -------------------
__global__ __launch_bounds__(256)
void k3(const float* __restrict__ cpart, float* __restrict__ diag) {
    int b = blockIdx.x;
    int t = threadIdx.x;
    int c16 = t & 15, rg = t >> 4;   // 16 row-groups x 16 rows
    int col = b * 16 + c16;
    float s = 0.f;
    #pragma unroll
    for (int i = 0; i < 16; ++i)
        s += cpart[(size_t)(rg * 16 + i) * DIM + col];
    __shared__ float red[16][16];
    red[rg][c16] = s;
    __syncthreads();
    if (rg == 0) {
        float tot = 0.f;
        #pragma unroll
        for (int g = 0; g < 16; ++g) tot += red[g][c16];
        diag[col] = tot;
    }
}

// ---- K4: split-K GEMM, 512 blocks: 64 tiles (8x8 of 32x32) x 8 k-slices ----------
__global__ __launch_bounds__(256)
void k4(const float* __restrict__ txt, const float* __restrict__ diag,
        const float* __restrict__ vmean, float* __restrict__ part) {
    __shared__ float Tt[32][PADK];
    __shared__ float Vt[32][PADK];
    int bx   = blockIdx.x;
    int tile = bx & 63;
    int ks   = bx >> 6;
    int i0 = (tile & 7) * 32, j0 = (tile >> 3) * 32;
    int kb = ks * TK;
    int t  = threadIdx.x;
    int tx = t & 15, ty = t >> 4;
    #pragma unroll
    for (int p = 0; p < 4; ++p) {
        int fid = p * 256 + t;
        int row = fid >> 5;
        int kq  = fid & 31;
        float4 a  = *(const float4*)(txt + (size_t)(i0 + row) * DIM + kb + kq * 4);
        float4 dg = *(const float4*)(diag + kb + kq * 4);
        a.x *= dg.x; a.y *= dg.y; a.z *= dg.z; a.w *= dg.w;
        *(float4*)&Tt[row][kq * 4] = a;
        float4 bb = *(const float4*)(vmean + (size_t)(j0 + row) * DIM + kb + kq * 4);
        *(float4*)&Vt[row][kq * 4] = bb;
    }
    __syncthreads();
    float acc00 = 0.f, acc01 = 0.f, acc10 = 0.f, acc11 = 0.f;
    #pragma unroll
    for (int k4i = 0; k4i < TK / 4; ++k4i) {
        float4 a0 = *(float4*)&Tt[ty * 2 + 0][k4i * 4];
        float4 a1 = *(float4*)&Tt[ty * 2 + 1][k4i * 4];
        float4 b0 = *(float4*)&Vt[tx * 2 + 0][k4i * 4];
        float4 b1 = *(float4*)&Vt[tx * 2 + 1][k4i * 4];
        acc00 = fmaf(a0.x, b0.x, acc00); acc00 = fmaf(a0.y, b0.y, acc00);
        acc00 = fmaf(a0.z, b0.z, acc00); acc00 = fmaf(a0.w, b0.w, acc00);
        acc01 = fmaf(a0.x, b1.x, acc01); acc01 = fmaf(a0.y, b1.y, acc01);
        acc01 = fmaf(a0.z, b1.z, acc01); acc01 = fmaf(a0.w, b1.w, acc01);
        acc10 = fmaf(a1.x, b0.x, acc10); acc10 = fmaf(a1.y, b0.y, acc10);
        acc10 = fmaf(a1.z, b0.z, acc10); acc10 = fmaf(a1.w, b0.w, acc10);
        acc11 = fmaf(a1.x, b1.x, acc11); acc11 = fmaf(a1.y, b1.y, acc11);
        acc11 = fmaf(a1.z, b1.z, acc11); acc11 = fmaf(a1.w, b1.w, acc11);
    }
    size_t base = (size_t)ks * (NB * NB);
    part[base + (size_t)(i0 + ty*2 + 0) * NB + j0 + tx*2 + 0] = acc00;
    part[base + (size_t)(i0 + ty*2 + 0) * NB + j0 + tx*2 + 1] = acc01;
    part[base + (size_t)(i0 + ty*2 + 1) * NB + j0 + tx*2 + 0] = acc10;
    part[base + (size_t)(i0 + ty*2 + 1) * NB + j0 + tx*2 + 1] = acc11;
}

// ---- K5: sum split-K partials + row-wise L2 norm ---------------------------------
__global__ __launch_bounds__(256)
void k5(const float* __restrict__ part, float* __restrict__ out) {
    int i = blockIdx.x, j = threadIdx.x;
    float s = 0.f;
    #pragma unroll
    for (int ks = 0; ks < KS; ++ks)
        s += part[(size_t)ks * (NB * NB) + (size_t)i * NB + j];
    float ss = s * s;
    #pragma unroll
    for (int off = 32; off > 0; off >>= 1) ss += __shfl_down(ss, off);
    __shared__ float red[4];
    int wid = j >> 6, lane = j & 63;
    if (lane == 0) red[wid] = ss;
    __syncthreads();
    float norm = sqrtf(red[0] + red[1] + red[2] + red[3]);
    out[(size_t)i * NB + j] = s / (norm + 1e-8f);
}

extern "C" void kernel_launch(void* const* d_in, const int* in_sizes, int n_in,
                              void* d_out, int out_size, void* d_ws, size_t ws_size,
                              hipStream_t stream) {
    const float* txt   = (const float*)d_in[0];   // [256,1024]
    const float* vid   = (const float*)d_in[1];   // [256,64,1024]
    const float* emb   = (const float*)d_in[2];   // [1024,1024]
    const float* simw  = (const float*)d_in[3];   // [1,1024]
    const float* tempw = (const float*)d_in[4];   // [1,1]
    float* out = (float*)d_out;                   // [256,256]

    char* ws = (char*)d_ws;
    float* thres = (float*)(ws);                                   // 4 KB
    float* diag  = (float*)(ws + 4096);                            // 4 KB
    float* cpart = (float*)(ws + 8192);                            // 1 MB
    float* vmean = (float*)(ws + 8192 + (1u << 20));               // 1 MB
    float* part  = (float*)(ws + 8192 + (2u << 20));               // 2 MB

    k1<<<1024, 256, 0, stream>>>(vid, emb, simw, vmean, thres);
    k2<<<256,  256, 0, stream>>>(emb, thres, tempw, cpart);
    k3<<<64,   256, 0, stream>>>(cpart, diag);
    k4<<<512,  256, 0, stream>>>(txt, diag, vmean, part);
    k5<<<256,  256, 0, stream>>>(part, out);
}